// Round 16
// baseline (238.534 us; speedup 1.0000x reference)
//
#include <hip/hip_runtime.h>
#include <cstdint>
#include <cstddef>
#include <math.h>

#define B_   2
#define T_   2048
#define DM   1024
#define NH   16
#define DH   64
#define DC1  384
#define DCC  256
#define DR   32
#define BT   (B_*T_)
#define DQK  96      // DH + DR

typedef __bf16 bf16x8 __attribute__((ext_vector_type(8)));
typedef __bf16 bf16x4 __attribute__((ext_vector_type(4)));
typedef float  f32x4  __attribute__((ext_vector_type(4)));
#define MFMA16(a,b,c) __builtin_amdgcn_mfma_f32_16x16x32_bf16((a),(b),(c),0,0,0)

__device__ __forceinline__ void gld16(const __bf16* g, __bf16* l) {
  __builtin_amdgcn_global_load_lds(
      (const __attribute__((address_space(1))) void*)g,
      (__attribute__((address_space(3))) void*)l, 16, 0, 0);
}

struct GemmDesc {
  const __bf16* A;
  const __bf16* Bt;
  void* C;
  int lda, ldb, ldc, K, Nvalid, ntx, blk0;
};
struct GemmBatch { GemmDesc d[4]; int nd; };

// ---------------------------------------------------------------------------
// Multi-GEMM, single-barrier double-buffered gld16 pipeline, BK=64, 4 waves.
// PROVEN CORRECT. Used for the fused mid-chain dispatch (already 28 waves/CU).
// ---------------------------------------------------------------------------
template<typename CT, int TM, int TN>
__global__ __launch_bounds__(256) void gemm_multi(GemmBatch gb) {
  constexpr int MT  = TM / 32;
  constexpr int NT  = TN / 32;
  constexpr int APW = (TM * 4) / 256;
  constexpr int BPW = (TN * 4) / 256;
  __shared__ __align__(16) __bf16 As[4 * TM * 32];
  __shared__ __align__(16) __bf16 Bs[4 * TN * 32];
  const int bid = blockIdx.x;
  int di = gb.nd - 1;
  while (di > 0 && bid < gb.d[di].blk0) di--;
  const GemmDesc D = gb.d[di];
  const int local = bid - D.blk0;
  const int by = local / D.ntx, bx = local - by * D.ntx;
  const int m0 = by * TM, n0 = bx * TN;

  const int tid = threadIdx.x;
  const int w = tid >> 6, l = tid & 63;
  const int g = l >> 4, ln = l & 15;
  const int wm = w >> 1, wn = w & 1;

  const __bf16* gA[APW]; int aoff[APW];
  #pragma unroll
  for (int i = 0; i < APW; i++) {
    int slot = w * (APW * 64) + i * 64 + l;
    gA[i] = D.A + (size_t)(m0 + (slot >> 2)) * D.lda + (slot & 3) * 8;
    aoff[i] = (w * (APW * 64) + i * 64) * 8;
  }
  const __bf16* gB[BPW]; int boff[BPW];
  #pragma unroll
  for (int i = 0; i < BPW; i++) {
    int slot = w * (BPW * 64) + i * 64 + l;
    int bn = n0 + (slot >> 2); if (bn >= D.Nvalid) bn = D.Nvalid - 1;
    gB[i] = D.Bt + (size_t)bn * D.ldb + (slot & 3) * 8;
    boff[i] = (w * (BPW * 64) + i * 64) * 8;
  }

  f32x4 acc[MT][NT];
  #pragma unroll
  for (int i = 0; i < MT; i++)
    #pragma unroll
    for (int j = 0; j < NT; j++) acc[i][j] = (f32x4){0.f, 0.f, 0.f, 0.f};

  #pragma unroll
  for (int ch = 0; ch < 2; ch++) {
    #pragma unroll
    for (int i = 0; i < APW; i++)
      gld16(gA[i] + ch * 32, As + ch * TM * 32 + aoff[i]);
    #pragma unroll
    for (int i = 0; i < BPW; i++)
      gld16(gB[i] + ch * 32, Bs + ch * TN * 32 + boff[i]);
  }

  const int nper = D.K >> 6;
  int p = 0;
  for (int it = 0; it < nper; ++it) {
    __syncthreads();
    if (it + 1 < nper) {
      const int ko = (it + 1) * 64;
      #pragma unroll
      for (int ch = 0; ch < 2; ch++) {
        #pragma unroll
        for (int i = 0; i < APW; i++)
          gld16(gA[i] + ko + ch * 32, As + ((p ^ 1) * 2 + ch) * TM * 32 + aoff[i]);
        #pragma unroll
        for (int i = 0; i < BPW; i++)
          gld16(gB[i] + ko + ch * 32, Bs + ((p ^ 1) * 2 + ch) * TN * 32 + boff[i]);
      }
    }
    #pragma unroll
    for (int ch = 0; ch < 2; ch++) {
      bf16x8 af[MT], bfr[NT];
      #pragma unroll
      for (int mt = 0; mt < MT; mt++)
        af[mt] = *(const bf16x8*)(As + (p * 2 + ch) * TM * 32 +
                                  (wm * (TM/2) + mt * 16 + ln) * 32 + g * 8);
      #pragma unroll
      for (int nt = 0; nt < NT; nt++)
        bfr[nt] = *(const bf16x8*)(Bs + (p * 2 + ch) * TN * 32 +
                                   (wn * (TN/2) + nt * 16 + ln) * 32 + g * 8);
      #pragma unroll
      for (int mt = 0; mt < MT; mt++)
        #pragma unroll
        for (int nt = 0; nt < NT; nt++)
          acc[mt][nt] = MFMA16(af[mt], bfr[nt], acc[mt][nt]);
    }
    p ^= 1;
  }

  CT* C = (CT*)D.C;
  #pragma unroll
  for (int mt = 0; mt < MT; mt++)
    #pragma unroll
    for (int r = 0; r < 4; r++) {
      int m = m0 + wm * (TM/2) + mt * 16 + g * 4 + r;
      #pragma unroll
      for (int nt = 0; nt < NT; nt++) {
        int n = n0 + wn * (TN/2) + nt * 16 + ln;
        if (n < D.Nvalid) C[(size_t)m * D.ldc + n] = (CT)acc[mt][nt][r];
      }
    }
}

// ---------------------------------------------------------------------------
// 8-wave (512-thread) 64x64 GEMM, BK=64 — for grid-limited dispatches
// (G1: 704 blk, G4: 1024 blk). Wave grid 4x2, wave tile 16x32 (2 MFMA per
// panel per wave). Staging: thread t issues exactly 1 A-slot + 1 B-slot
// gld16 per iter; waves 0-3 cover k-panel 0, waves 4-7 panel 1 (wave-uniform
// LDS bases). Same MFMA k-order as gemm_multi -> bit-identical results.
// LDS = 32 KB. Doubles waves/CU vs the 4-wave version at the same grid.
// ---------------------------------------------------------------------------
template<typename CT>
__global__ __launch_bounds__(512) void gemm_mm8(GemmBatch gb) {
  __shared__ __align__(16) __bf16 As[2 * 2 * 2048];   // [buf][panel][64*32]
  __shared__ __align__(16) __bf16 Bs[2 * 2 * 2048];
  const int bid = blockIdx.x;
  int di = gb.nd - 1;
  while (di > 0 && bid < gb.d[di].blk0) di--;
  const GemmDesc D = gb.d[di];
  const int local = bid - D.blk0;
  const int by = local / D.ntx, bx = local - by * D.ntx;
  const int m0 = by * 64, n0 = bx * 64;

  const int tid = threadIdx.x;
  const int w = tid >> 6, l = tid & 63;
  const int g = l >> 4, ln = l & 15;
  const int wm = w >> 1, wn = w & 1;   // wave grid 4x2
  const int pa = w >> 2;               // k-panel this wave stages (uniform)
  const int w4 = w & 3;

  // staging coords: within-panel slot = w4*64 + l (256 slots = 64 rows x 4)
  const int arow = w4 * 16 + (l >> 2);
  const int ac4  = l & 3;
  const __bf16* gA = D.A + (size_t)(m0 + arow) * D.lda + pa * 32 + ac4 * 8;
  const int aoff = pa * 2048 + w4 * 512;   // wave-uniform elem base (+ l*8)

  int bn = n0 + arow; if (bn >= D.Nvalid) bn = D.Nvalid - 1;
  const __bf16* gB = D.Bt + (size_t)bn * D.ldb + pa * 32 + ac4 * 8;
  const int boff = aoff;

  f32x4 acc[2];
  acc[0] = (f32x4){0.f, 0.f, 0.f, 0.f};
  acc[1] = (f32x4){0.f, 0.f, 0.f, 0.f};

  // prime buffer 0 (both panels covered collectively by the 8 waves)
  gld16(gA, As + aoff);
  gld16(gB, Bs + boff);

  const int nper = D.K >> 6;
  int p = 0;
  for (int it = 0; it < nper; ++it) {
    __syncthreads();            // drains vmcnt -> buf[p] ready
    if (it + 1 < nper) {
      const int ko = (it + 1) * 64;
      gld16(gA + ko, As + (p ^ 1) * 4096 + aoff);
      gld16(gB + ko, Bs + (p ^ 1) * 4096 + boff);
    }
    #pragma unroll
    for (int ch = 0; ch < 2; ch++) {
      const int base = p * 4096 + ch * 2048;
      bf16x8 af  = *(const bf16x8*)(As + base + (wm * 16 + ln) * 32 + g * 8);
      bf16x8 bf0 = *(const bf16x8*)(Bs + base + (wn * 32 + ln) * 32 + g * 8);
      bf16x8 bf1 = *(const bf16x8*)(Bs + base + (wn * 32 + 16 + ln) * 32 + g * 8);
      acc[0] = MFMA16(af, bf0, acc[0]);
      acc[1] = MFMA16(af, bf1, acc[1]);
    }
    p ^= 1;
  }

  CT* C = (CT*)D.C;
  #pragma unroll
  for (int nt = 0; nt < 2; nt++)
    #pragma unroll
    for (int r = 0; r < 4; r++) {
      int m = m0 + wm * 16 + g * 4 + r;
      int n = n0 + wn * 32 + nt * 16 + ln;
      if (n < D.Nvalid) C[(size_t)m * D.ldc + n] = (CT)acc[nt][r];
    }
}

// ---------------------------------------------------------------------------
// Fused weight prep: 8 matrices fp32 [K,N] -> bf16 transposed [N,K].
// ---------------------------------------------------------------------------
struct TDescs {
  const float* src[8];
  __bf16* dst[8];
  int K[8];
  int N[8];
  int t0[9];
};

__global__ __launch_bounds__(256) void transpose_cast_all(TDescs td) {
  __shared__ float t[32][33];
  int bx = blockIdx.x;
  int i = 7;
  while (bx < td.t0[i]) i--;
  int local = bx - td.t0[i];
  int ntn = td.N[i] >> 5;
  int kt = local / ntn;
  int nt = local - kt * ntn;
  const int ks = kt * 32, ns = nt * 32;
  const float* src = td.src[i];
  __bf16* dst = td.dst[i];
  const int K = td.K[i], N = td.N[i];
  const int tx = threadIdx.x, ty = threadIdx.y;
  #pragma unroll
  for (int r = 0; r < 4; r++)
    t[ty + r * 8][tx] = src[(size_t)(ks + ty + r * 8) * N + ns + tx];
  __syncthreads();
  #pragma unroll
  for (int r = 0; r < 4; r++)
    dst[(size_t)(ns + ty + r * 8) * K + ks + tx] = (__bf16)t[tx][ty + r * 8];
  (void)K;
}

__global__ __launch_bounds__(256) void cast_f32_bf16(
    const float* __restrict__ src, __bf16* __restrict__ dst) {
  int i = (blockIdx.x * 256 + threadIdx.x) * 4;
  float4 v = *(const float4*)(src + i);
  bf16x4 o = { (__bf16)v.x, (__bf16)v.y, (__bf16)v.z, (__bf16)v.w };
  *(bf16x4*)(dst + i) = o;
}

// ---------------------------------------------------------------------------
// Assemble: per (row, head) wave -> RoPE + concat + RMS-norm.
// ---------------------------------------------------------------------------
__global__ __launch_bounds__(256) void assemble_qk(
    const __bf16* __restrict__ qsqr,  // [BT][1536]: qs | qr
    const __bf16* __restrict__ kv,    // [BT][1024]: ks
    const __bf16* __restrict__ cqkr,  // [BT][672]: kr at cols 640..671
    __bf16* __restrict__ qb, __bf16* __restrict__ kb) {
  int wid  = (blockIdx.x * blockDim.x + threadIdx.x) >> 6;
  int lane = threadIdx.x & 63;
  int h   = wid & (NH - 1);
  int row = wid >> 4;
  int b   = row >> 11;
  int t   = row & (T_ - 1);

  float v0q = (float)qsqr[(size_t)row * 1536 + h * DH + lane];
  float v0k = (float)kv[(size_t)row * 1024 + h * DH + lane];
  float v1q = 0.f, v1k = 0.f;
  if (lane < DR) {
    int j  = lane;
    int jj = j & 15;
    float invf = powf(10000.f, -(float)jj / 16.f);
    float ang  = (float)t * invf;
    float s, c;
    sincosf(ang, &s, &c);
    float qx1 = (float)qsqr[(size_t)row * 1536 + 1024 + h * DR + jj];
    float qx2 = (float)qsqr[(size_t)row * 1536 + 1024 + h * DR + 16 + jj];
    float kx1 = (float)cqkr[(size_t)row * 672 + 640 + jj];
    float kx2 = (float)cqkr[(size_t)row * 672 + 640 + 16 + jj];
    if (j < 16) { v1q = qx1 * c - qx2 * s; v1k = kx1 * c - kx2 * s; }
    else        { v1q = qx1 * s + qx2 * c; v1k = kx1 * s + kx2 * c; }
  }
  float ssq = v0q * v0q + v1q * v1q;
  float ssk = v0k * v0k + v1k * v1k;
  #pragma unroll
  for (int off = 32; off; off >>= 1) {
    ssq += __shfl_xor(ssq, off);
    ssk += __shfl_xor(ssk, off);
  }
  float sq = rsqrtf(ssq / 96.f + 1e-6f);
  float sk = rsqrtf(ssk / 96.f + 1e-6f);
  size_t obase = ((size_t)(b * NH + h) * T_ + t) * DQK;
  qb[obase + lane] = (__bf16)(v0q * sq);
  kb[obase + lane] = (__bf16)(v0k * sk);
  if (lane < DR) {
    qb[obase + DH + lane] = (__bf16)(v1q * sq);
    kb[obase + DH + lane] = (__bf16)(v1k * sk);
  }
}

// ---------------------------------------------------------------------------
// Fixed-max MFMA flash attention (causal), paired q-tiles, 8-wave blocks.
// Unchanged from r15 (passing, 57.8 us).
// ---------------------------------------------------------------------------
#define KS_STR 104   // K LDS row stride
#define VT_STR 72    // V^T / P row stride
__global__ __launch_bounds__(512) void flash_mfma(
    const __bf16* __restrict__ qg, const __bf16* __restrict__ kg,
    const __bf16* __restrict__ vt,  // [b*1024 + h*64 + d][T_]  (V^T)
    __bf16* __restrict__ ao) {
  __shared__ __align__(16) __bf16 Ksh[64 * KS_STR];      // 13312 B
  __shared__ __align__(16) __bf16 Vth[64 * VT_STR];      //  9216 B
  __shared__ __align__(16) __bf16 Psh[8 * 16 * VT_STR];  // 18432 B

  const int hb = blockIdx.y;
  const int bb = hb >> 4, h = hb & 15;
  const int ta = blockIdx.x;                 // light tile 0..15
  const int tb = (T_ / 64 - 1) - ta;         // heavy tile 31..16
  const int w    = threadIdx.x >> 6;         // 0..7
  const int lane = threadIdx.x & 63;
  const int g    = lane >> 4;
  const int ln   = lane & 15;
  const int wi   = w & 3;
  const int tile = (w < 4) ? tb : ta;        // wave's tile
  const int qw   = tile * 64 + wi * 16;      // wave's 16 queries
  const float scale = 0.10206207261596577f;  // 1/sqrt(96)
  const size_t hbT = (size_t)hb * T_;
  const __bf16* vrow = vt + (size_t)(bb * 1024 + h * 64) * T_;

  const int ks0   = threadIdx.x;
  const int krow0 = ks0 / 12, kcol0 = ks0 % 12;
  const bool k1on = (threadIdx.x < 256);
  const int ks1   = 512 + threadIdx.x;
  const int krow1 = ks1 / 12, kcol1 = ks1 % 12;
  const int vr = threadIdx.x >> 3, vc = threadIdx.x & 7;

  bf16x8 qf[3];
  #pragma unroll
  for (int s = 0; s < 3; s++)
    qf[s] = *(const bf16x8*)(qg + (hbT + qw + ln) * DQK + s * 32 + g * 8);

  f32x4 o[4];
  #pragma unroll
  for (int nt = 0; nt < 4; nt++) o[nt] = (f32x4){0.f, 0.f, 0.f, 0.f};
  float lsum[4] = {};

  __bf16* Pw = Psh + w * 16 * VT_STR;
  const int kmax = (tb + 1) * 64;

  bf16x8 kreg0, kreg1, vreg;
  kreg0 = *(const bf16x8*)(kg + (hbT + krow0) * DQK + kcol0 * 8);
  if (k1on) kreg1 = *(const bf16x8*)(kg + (hbT + krow1) * DQK + kcol1 * 8);
  vreg = *(const bf16x8*)(vrow + (size_t)vr * T_ + vc * 8);

  for (int k0 = 0; k0 < kmax; k0 += 64) {
    __syncthreads();   // previous compute done reading Ksh/Vth
    *(bf16x8*)(Ksh + krow0 * KS_STR + kcol0 * 8) = kreg0;
    if (k1on) *(bf16x8*)(Ksh + krow1 * KS_STR + kcol1 * 8) = kreg1;
    *(bf16x8*)(Vth + vr * VT_STR + vc * 8) = vreg;
    __syncthreads();
    if (k0 + 64 < kmax) {   // prefetch next tile into regs (hidden by compute)
      kreg0 = *(const bf16x8*)(kg + (hbT + k0 + 64 + krow0) * DQK + kcol0 * 8);
      if (k1on)
        kreg1 = *(const bf16x8*)(kg + (hbT + k0 + 64 + krow1) * DQK + kcol1 * 8);
      vreg = *(const bf16x8*)(vrow + (size_t)vr * T_ + k0 + 64 + vc * 8);
    }

    if (k0 <= qw + 15) {   // wave-uniform causal skip
      f32x4 sa[4];
      #pragma unroll
      for (int ks = 0; ks < 4; ks++) sa[ks] = (f32x4){0.f, 0.f, 0.f, 0.f};
      #pragma unroll
      for (int s = 0; s < 3; s++)
        #pragma unroll
        for (int ks = 0; ks < 4; ks++) {
          bf16x8 kf = *(const bf16x8*)(Ksh + (ks * 16 + ln) * KS_STR + s * 32 + g * 8);
          sa[ks] = MFMA16(qf[s], kf, sa[ks]);
        }
      const bool diag = (k0 + 63 > qw);
      #pragma unroll
      for (int ks = 0; ks < 4; ks++)
        #pragma unroll
        for (int r = 0; r < 4; r++) {
          float p = __expf(sa[ks][r] * scale);
          if (diag) {
            int q   = qw + g * 4 + r;
            int key = k0 + ks * 16 + ln;
            if (key > q) p = 0.f;
          }
          lsum[r] += p;
          Pw[(g * 4 + r) * VT_STR + ks * 16 + ln] = (__bf16)p;
        }
      #pragma unroll
      for (int ks2 = 0; ks2 < 2; ks2++) {
        bf16x8 pf = *(const bf16x8*)(Pw + ln * VT_STR + ks2 * 32 + g * 8);
        #pragma unroll
        for (int nt = 0; nt < 4; nt++) {
          bf16x8 vf = *(const bf16x8*)(Vth + (nt * 16 + ln) * VT_STR + ks2 * 32 + g * 8);
          o[nt] = MFMA16(pf, vf, o[nt]);
        }
      }
    }
  }

  float linv[4];
  #pragma unroll
  for (int r = 0; r < 4; r++) {
    float s = lsum[r];
    s += __shfl_xor(s, 1); s += __shfl_xor(s, 2);
    s += __shfl_xor(s, 4); s += __shfl_xor(s, 8);
    linv[r] = 1.0f / s;
  }

  #pragma unroll
  for (int nt = 0; nt < 4; nt++)
    #pragma unroll
    for (int r = 0; r < 4; r++) {
      int q = qw + g * 4 + r;
      ao[(size_t)(bb * T_ + q) * DM + h * DH + nt * 16 + ln] =
          (__bf16)(o[nt][r] * linv[r]);
    }
}

// ---------------------------------------------------------------------------
extern "C" void kernel_launch(void* const* d_in, const int* in_sizes, int n_in,
                              void* d_out, int out_size, void* d_ws, size_t ws_size,
                              hipStream_t stream) {
  const float* x     = (const float*)d_in[0];
  const float* w_dq  = (const float*)d_in[1];
  const float* w_uq  = (const float*)d_in[2];
  const float* w_rq  = (const float*)d_in[3];
  const float* w_dkv = (const float*)d_in[4];
  const float* w_rk  = (const float*)d_in[5];
  const float* w_uk  = (const float*)d_in[6];
  const float* w_uv  = (const float*)d_in[7];
  const float* w_o   = (const float*)d_in[8];
  float* out = (float*)d_out;

  __bf16* p = (__bf16*)d_ws;
  __bf16* xb   = p;  p += (size_t)BT * DM;
  __bf16* B1t  = p;  p += (size_t)672 * 1024;
  __bf16* B2t  = p;  p += (size_t)1536 * 384;
  __bf16* B3t  = p;  p += (size_t)2048 * 256;   // w_uk^T | w_uv^T
  __bf16* B4t  = p;  p += (size_t)1024 * 1024;
  __bf16* cqkr = p;  p += (size_t)BT * 672;     // c_q | c_kv | kr
  __bf16* qsqr = p;  p += (size_t)BT * 1536;    // qs | qr
  __bf16* kv   = p;  p += (size_t)BT * 1024;    // ks
  __bf16* vt   = p;  p += (size_t)BT * 1024;    // V^T [b*1024+h*64+d][T]
  __bf16* qb   = p;  p += (size_t)B_ * NH * T_ * DQK;
  __bf16* kb   = p;  p += (size_t)B_ * NH * T_ * DQK;
  __bf16* aob  = xb;   // xb dead after G1

  // Prep: cast x; fused transpose of all 8 weights
  cast_f32_bf16<<<(BT * DM) / 1024, 256, 0, stream>>>(x, xb);
  {
    TDescs td;
    const float* srcs[8] = {w_dq, w_dkv, w_rk, w_uq, w_rq, w_uk, w_uv, w_o};
    __bf16* dsts[8] = {B1t, B1t + (size_t)384 * 1024, B1t + (size_t)640 * 1024,
                       B2t, B2t + (size_t)1024 * 384,
                       B3t, B3t + (size_t)1024 * 256, B4t};
    int Ks[8] = {1024, 1024, 1024, 384, 384, 256, 256, 1024};
    int Ns[8] = {384, 256, 32, 1024, 512, 1024, 1024, 1024};
    int acc = 0;
    for (int i = 0; i < 8; i++) {
      td.src[i] = srcs[i]; td.dst[i] = dsts[i];
      td.K[i] = Ks[i]; td.N[i] = Ns[i];
      td.t0[i] = acc;
      acc += (Ks[i] / 32) * (Ns[i] / 32);
    }
    td.t0[8] = acc;
    transpose_cast_all<<<acc, dim3(32, 8), 0, stream>>>(td);
  }

  // G1: cqkr = xb @ B1t^T   (64x64, BK=64, 8-wave: 704 blocks = 22 waves/CU)
  {
    GemmBatch g; g.nd = 1;
    g.d[0] = GemmDesc{xb, B1t, (void*)cqkr, DM, 1024, 672, 1024, 672, 11, 0};
    gemm_mm8<__bf16><<<704, 512, 0, stream>>>(g);
  }
  // Fused: G2 (qsqr), G3 (ks), VT batch 0/1  (64x128, BK=64: 1792 blocks)
  {
    GemmBatch g; g.nd = 4;
    g.d[0] = GemmDesc{cqkr, B2t, (void*)qsqr, 672, 384, 1536, 384, 1536, 12, 0};
    g.d[1] = GemmDesc{cqkr + 384, B3t, (void*)kv, 672, 256, 1024, 256, 1024, 8, 768};
    g.d[2] = GemmDesc{B3t + (size_t)1024 * 256, cqkr + 384, (void*)vt,
                      256, 672, T_, 256, T_, 16, 1280};
    g.d[3] = GemmDesc{B3t + (size_t)1024 * 256, cqkr + (size_t)T_ * 672 + 384,
                      (void*)(vt + (size_t)1024 * T_), 256, 672, T_, 256, T_, 16, 1536};
    gemm_multi<__bf16, 64, 128><<<1792, 256, 0, stream>>>(g);
  }

  // RoPE + concat + RMS-norm
  assemble_qk<<<(BT * NH) / 4, 256, 0, stream>>>(qsqr, kv, cqkr, qb, kb);

  // Paired-tile fixed-max causal MFMA flash attention (8-wave blocks)
  flash_mfma<<<dim3(T_ / 128, B_ * NH), 512, 0, stream>>>(qb, kb, vt, aob);

  // G4: out = aob @ B4t^T  (fp32 out, 64x64, BK=64, 8-wave: 1024 blocks = 32 waves/CU)
  {
    GemmBatch g; g.nd = 1;
    g.d[0] = GemmDesc{aob, B4t, (void*)out, DM, 1024, DM, 1024, 1024, 16, 0};
    gemm_mm8<float><<<1024, 512, 0, stream>>>(g);
  }
}

// Round 17
// 235.711 us; speedup vs baseline: 1.0120x; 1.0120x over previous
//
#include <hip/hip_runtime.h>
#include <cstdint>
#include <cstddef>
#include <math.h>

#define B_   2
#define T_   2048
#define DM   1024
#define NH   16
#define DH   64
#define DC1  384
#define DCC  256
#define DR   32
#define BT   (B_*T_)
#define DQK  96      // DH + DR

typedef __bf16 bf16x8 __attribute__((ext_vector_type(8)));
typedef __bf16 bf16x4 __attribute__((ext_vector_type(4)));
typedef float  f32x4  __attribute__((ext_vector_type(4)));
#define MFMA16(a,b,c) __builtin_amdgcn_mfma_f32_16x16x32_bf16((a),(b),(c),0,0,0)

__device__ __forceinline__ void gld16(const __bf16* g, __bf16* l) {
  __builtin_amdgcn_global_load_lds(
      (const __attribute__((address_space(1))) void*)g,
      (__attribute__((address_space(3))) void*)l, 16, 0, 0);
}

struct GemmDesc {
  const __bf16* A;
  const __bf16* Bt;
  void* C;
  int lda, ldb, ldc, K, Nvalid, ntx, blk0;
};
struct GemmBatch { GemmDesc d[4]; int nd; };

// ---------------------------------------------------------------------------
// Multi-GEMM, single-barrier double-buffered gld16 pipeline, BK=64, 4 waves.
// PROVEN CORRECT (r10-r12 bit-identical experiment). TMxTN in {64,128}.
// 128x128: 32 MFMA : 16 ds_read_b128 per wave-iter (m97 density), LDS 64 KB.
// ---------------------------------------------------------------------------
template<typename CT, int TM, int TN>
__global__ __launch_bounds__(256) void gemm_multi(GemmBatch gb) {
  constexpr int MT  = TM / 32;
  constexpr int NT  = TN / 32;
  constexpr int APW = (TM * 4) / 256;
  constexpr int BPW = (TN * 4) / 256;
  __shared__ __align__(16) __bf16 As[4 * TM * 32];
  __shared__ __align__(16) __bf16 Bs[4 * TN * 32];
  const int bid = blockIdx.x;
  int di = gb.nd - 1;
  while (di > 0 && bid < gb.d[di].blk0) di--;
  const GemmDesc D = gb.d[di];
  const int local = bid - D.blk0;
  const int by = local / D.ntx, bx = local - by * D.ntx;
  const int m0 = by * TM, n0 = bx * TN;

  const int tid = threadIdx.x;
  const int w = tid >> 6, l = tid & 63;
  const int g = l >> 4, ln = l & 15;
  const int wm = w >> 1, wn = w & 1;

  const __bf16* gA[APW]; int aoff[APW];
  #pragma unroll
  for (int i = 0; i < APW; i++) {
    int slot = w * (APW * 64) + i * 64 + l;
    gA[i] = D.A + (size_t)(m0 + (slot >> 2)) * D.lda + (slot & 3) * 8;
    aoff[i] = (w * (APW * 64) + i * 64) * 8;
  }
  const __bf16* gB[BPW]; int boff[BPW];
  #pragma unroll
  for (int i = 0; i < BPW; i++) {
    int slot = w * (BPW * 64) + i * 64 + l;
    int bn = n0 + (slot >> 2); if (bn >= D.Nvalid) bn = D.Nvalid - 1;
    gB[i] = D.Bt + (size_t)bn * D.ldb + (slot & 3) * 8;
    boff[i] = (w * (BPW * 64) + i * 64) * 8;
  }

  f32x4 acc[MT][NT];
  #pragma unroll
  for (int i = 0; i < MT; i++)
    #pragma unroll
    for (int j = 0; j < NT; j++) acc[i][j] = (f32x4){0.f, 0.f, 0.f, 0.f};

  #pragma unroll
  for (int ch = 0; ch < 2; ch++) {
    #pragma unroll
    for (int i = 0; i < APW; i++)
      gld16(gA[i] + ch * 32, As + ch * TM * 32 + aoff[i]);
    #pragma unroll
    for (int i = 0; i < BPW; i++)
      gld16(gB[i] + ch * 32, Bs + ch * TN * 32 + boff[i]);
  }

  const int nper = D.K >> 6;
  int p = 0;
  for (int it = 0; it < nper; ++it) {
    __syncthreads();
    if (it + 1 < nper) {
      const int ko = (it + 1) * 64;
      #pragma unroll
      for (int ch = 0; ch < 2; ch++) {
        #pragma unroll
        for (int i = 0; i < APW; i++)
          gld16(gA[i] + ko + ch * 32, As + ((p ^ 1) * 2 + ch) * TM * 32 + aoff[i]);
        #pragma unroll
        for (int i = 0; i < BPW; i++)
          gld16(gB[i] + ko + ch * 32, Bs + ((p ^ 1) * 2 + ch) * TN * 32 + boff[i]);
      }
    }
    #pragma unroll
    for (int ch = 0; ch < 2; ch++) {
      bf16x8 af[MT], bfr[NT];
      #pragma unroll
      for (int mt = 0; mt < MT; mt++)
        af[mt] = *(const bf16x8*)(As + (p * 2 + ch) * TM * 32 +
                                  (wm * (TM/2) + mt * 16 + ln) * 32 + g * 8);
      #pragma unroll
      for (int nt = 0; nt < NT; nt++)
        bfr[nt] = *(const bf16x8*)(Bs + (p * 2 + ch) * TN * 32 +
                                   (wn * (TN/2) + nt * 16 + ln) * 32 + g * 8);
      #pragma unroll
      for (int mt = 0; mt < MT; mt++)
        #pragma unroll
        for (int nt = 0; nt < NT; nt++)
          acc[mt][nt] = MFMA16(af[mt], bfr[nt], acc[mt][nt]);
    }
    p ^= 1;
  }

  CT* C = (CT*)D.C;
  #pragma unroll
  for (int mt = 0; mt < MT; mt++)
    #pragma unroll
    for (int r = 0; r < 4; r++) {
      int m = m0 + wm * (TM/2) + mt * 16 + g * 4 + r;
      #pragma unroll
      for (int nt = 0; nt < NT; nt++) {
        int n = n0 + wn * (TN/2) + nt * 16 + ln;
        if (n < D.Nvalid) C[(size_t)m * D.ldc + n] = (CT)acc[mt][nt][r];
      }
    }
}

// ---------------------------------------------------------------------------
// Fused weight prep: 8 matrices fp32 [K,N] -> bf16 transposed [N,K].
// ---------------------------------------------------------------------------
struct TDescs {
  const float* src[8];
  __bf16* dst[8];
  int K[8];
  int N[8];
  int t0[9];
};

__global__ __launch_bounds__(256) void transpose_cast_all(TDescs td) {
  __shared__ float t[32][33];
  int bx = blockIdx.x;
  int i = 7;
  while (bx < td.t0[i]) i--;
  int local = bx - td.t0[i];
  int ntn = td.N[i] >> 5;
  int kt = local / ntn;
  int nt = local - kt * ntn;
  const int ks = kt * 32, ns = nt * 32;
  const float* src = td.src[i];
  __bf16* dst = td.dst[i];
  const int K = td.K[i], N = td.N[i];
  const int tx = threadIdx.x, ty = threadIdx.y;
  #pragma unroll
  for (int r = 0; r < 4; r++)
    t[ty + r * 8][tx] = src[(size_t)(ks + ty + r * 8) * N + ns + tx];
  __syncthreads();
  #pragma unroll
  for (int r = 0; r < 4; r++)
    dst[(size_t)(ns + ty + r * 8) * K + ks + tx] = (__bf16)t[tx][ty + r * 8];
  (void)K;
}

__global__ __launch_bounds__(256) void cast_f32_bf16(
    const float* __restrict__ src, __bf16* __restrict__ dst) {
  int i = (blockIdx.x * 256 + threadIdx.x) * 4;
  float4 v = *(const float4*)(src + i);
  bf16x4 o = { (__bf16)v.x, (__bf16)v.y, (__bf16)v.z, (__bf16)v.w };
  *(bf16x4*)(dst + i) = o;
}

// ---------------------------------------------------------------------------
// Assemble: per (row, head) wave -> RoPE + concat + RMS-norm.
// ---------------------------------------------------------------------------
__global__ __launch_bounds__(256) void assemble_qk(
    const __bf16* __restrict__ qsqr,  // [BT][1536]: qs | qr
    const __bf16* __restrict__ kv,    // [BT][1024]: ks
    const __bf16* __restrict__ cqkr,  // [BT][672]: kr at cols 640..671
    __bf16* __restrict__ qb, __bf16* __restrict__ kb) {
  int wid  = (blockIdx.x * blockDim.x + threadIdx.x) >> 6;
  int lane = threadIdx.x & 63;
  int h   = wid & (NH - 1);
  int row = wid >> 4;
  int b   = row >> 11;
  int t   = row & (T_ - 1);

  float v0q = (float)qsqr[(size_t)row * 1536 + h * DH + lane];
  float v0k = (float)kv[(size_t)row * 1024 + h * DH + lane];
  float v1q = 0.f, v1k = 0.f;
  if (lane < DR) {
    int j  = lane;
    int jj = j & 15;
    float invf = powf(10000.f, -(float)jj / 16.f);
    float ang  = (float)t * invf;
    float s, c;
    sincosf(ang, &s, &c);
    float qx1 = (float)qsqr[(size_t)row * 1536 + 1024 + h * DR + jj];
    float qx2 = (float)qsqr[(size_t)row * 1536 + 1024 + h * DR + 16 + jj];
    float kx1 = (float)cqkr[(size_t)row * 672 + 640 + jj];
    float kx2 = (float)cqkr[(size_t)row * 672 + 640 + 16 + jj];
    if (j < 16) { v1q = qx1 * c - qx2 * s; v1k = kx1 * c - kx2 * s; }
    else        { v1q = qx1 * s + qx2 * c; v1k = kx1 * s + kx2 * c; }
  }
  float ssq = v0q * v0q + v1q * v1q;
  float ssk = v0k * v0k + v1k * v1k;
  #pragma unroll
  for (int off = 32; off; off >>= 1) {
    ssq += __shfl_xor(ssq, off);
    ssk += __shfl_xor(ssk, off);
  }
  float sq = rsqrtf(ssq / 96.f + 1e-6f);
  float sk = rsqrtf(ssk / 96.f + 1e-6f);
  size_t obase = ((size_t)(b * NH + h) * T_ + t) * DQK;
  qb[obase + lane] = (__bf16)(v0q * sq);
  kb[obase + lane] = (__bf16)(v0k * sk);
  if (lane < DR) {
    qb[obase + DH + lane] = (__bf16)(v1q * sq);
    kb[obase + DH + lane] = (__bf16)(v1k * sk);
  }
}

// ---------------------------------------------------------------------------
// Fixed-max MFMA flash attention (causal), paired q-tiles, 8-wave blocks.
// Unchanged from r15 (passing, 57.8 us).
// ---------------------------------------------------------------------------
#define KS_STR 104   // K LDS row stride
#define VT_STR 72    // V^T / P row stride
__global__ __launch_bounds__(512) void flash_mfma(
    const __bf16* __restrict__ qg, const __bf16* __restrict__ kg,
    const __bf16* __restrict__ vt,  // [b*1024 + h*64 + d][T_]  (V^T)
    __bf16* __restrict__ ao) {
  __shared__ __align__(16) __bf16 Ksh[64 * KS_STR];      // 13312 B
  __shared__ __align__(16) __bf16 Vth[64 * VT_STR];      //  9216 B
  __shared__ __align__(16) __bf16 Psh[8 * 16 * VT_STR];  // 18432 B

  const int hb = blockIdx.y;
  const int bb = hb >> 4, h = hb & 15;
  const int ta = blockIdx.x;                 // light tile 0..15
  const int tb = (T_ / 64 - 1) - ta;         // heavy tile 31..16
  const int w    = threadIdx.x >> 6;         // 0..7
  const int lane = threadIdx.x & 63;
  const int g    = lane >> 4;
  const int ln   = lane & 15;
  const int wi   = w & 3;
  const int tile = (w < 4) ? tb : ta;        // wave's tile
  const int qw   = tile * 64 + wi * 16;      // wave's 16 queries
  const float scale = 0.10206207261596577f;  // 1/sqrt(96)
  const size_t hbT = (size_t)hb * T_;
  const __bf16* vrow = vt + (size_t)(bb * 1024 + h * 64) * T_;

  const int ks0   = threadIdx.x;
  const int krow0 = ks0 / 12, kcol0 = ks0 % 12;
  const bool k1on = (threadIdx.x < 256);
  const int ks1   = 512 + threadIdx.x;
  const int krow1 = ks1 / 12, kcol1 = ks1 % 12;
  const int vr = threadIdx.x >> 3, vc = threadIdx.x & 7;

  bf16x8 qf[3];
  #pragma unroll
  for (int s = 0; s < 3; s++)
    qf[s] = *(const bf16x8*)(qg + (hbT + qw + ln) * DQK + s * 32 + g * 8);

  f32x4 o[4];
  #pragma unroll
  for (int nt = 0; nt < 4; nt++) o[nt] = (f32x4){0.f, 0.f, 0.f, 0.f};
  float lsum[4] = {};

  __bf16* Pw = Psh + w * 16 * VT_STR;
  const int kmax = (tb + 1) * 64;

  bf16x8 kreg0, kreg1, vreg;
  kreg0 = *(const bf16x8*)(kg + (hbT + krow0) * DQK + kcol0 * 8);
  if (k1on) kreg1 = *(const bf16x8*)(kg + (hbT + krow1) * DQK + kcol1 * 8);
  vreg = *(const bf16x8*)(vrow + (size_t)vr * T_ + vc * 8);

  for (int k0 = 0; k0 < kmax; k0 += 64) {
    __syncthreads();   // previous compute done reading Ksh/Vth
    *(bf16x8*)(Ksh + krow0 * KS_STR + kcol0 * 8) = kreg0;
    if (k1on) *(bf16x8*)(Ksh + krow1 * KS_STR + kcol1 * 8) = kreg1;
    *(bf16x8*)(Vth + vr * VT_STR + vc * 8) = vreg;
    __syncthreads();
    if (k0 + 64 < kmax) {   // prefetch next tile into regs (hidden by compute)
      kreg0 = *(const bf16x8*)(kg + (hbT + k0 + 64 + krow0) * DQK + kcol0 * 8);
      if (k1on)
        kreg1 = *(const bf16x8*)(kg + (hbT + k0 + 64 + krow1) * DQK + kcol1 * 8);
      vreg = *(const bf16x8*)(vrow + (size_t)vr * T_ + k0 + 64 + vc * 8);
    }

    if (k0 <= qw + 15) {   // wave-uniform causal skip
      f32x4 sa[4];
      #pragma unroll
      for (int ks = 0; ks < 4; ks++) sa[ks] = (f32x4){0.f, 0.f, 0.f, 0.f};
      #pragma unroll
      for (int s = 0; s < 3; s++)
        #pragma unroll
        for (int ks = 0; ks < 4; ks++) {
          bf16x8 kf = *(const bf16x8*)(Ksh + (ks * 16 + ln) * KS_STR + s * 32 + g * 8);
          sa[ks] = MFMA16(qf[s], kf, sa[ks]);
        }
      const bool diag = (k0 + 63 > qw);
      #pragma unroll
      for (int ks = 0; ks < 4; ks++)
        #pragma unroll
        for (int r = 0; r < 4; r++) {
          float p = __expf(sa[ks][r] * scale);
          if (diag) {
            int q   = qw + g * 4 + r;
            int key = k0 + ks * 16 + ln;
            if (key > q) p = 0.f;
          }
          lsum[r] += p;
          Pw[(g * 4 + r) * VT_STR + ks * 16 + ln] = (__bf16)p;
        }
      #pragma unroll
      for (int ks2 = 0; ks2 < 2; ks2++) {
        bf16x8 pf = *(const bf16x8*)(Pw + ln * VT_STR + ks2 * 32 + g * 8);
        #pragma unroll
        for (int nt = 0; nt < 4; nt++) {
          bf16x8 vf = *(const bf16x8*)(Vth + (nt * 16 + ln) * VT_STR + ks2 * 32 + g * 8);
          o[nt] = MFMA16(pf, vf, o[nt]);
        }
      }
    }
  }

  float linv[4];
  #pragma unroll
  for (int r = 0; r < 4; r++) {
    float s = lsum[r];
    s += __shfl_xor(s, 1); s += __shfl_xor(s, 2);
    s += __shfl_xor(s, 4); s += __shfl_xor(s, 8);
    linv[r] = 1.0f / s;
  }

  #pragma unroll
  for (int nt = 0; nt < 4; nt++)
    #pragma unroll
    for (int r = 0; r < 4; r++) {
      int q = qw + g * 4 + r;
      ao[(size_t)(bb * T_ + q) * DM + h * DH + nt * 16 + ln] =
          (__bf16)(o[nt][r] * linv[r]);
    }
}

// ---------------------------------------------------------------------------
extern "C" void kernel_launch(void* const* d_in, const int* in_sizes, int n_in,
                              void* d_out, int out_size, void* d_ws, size_t ws_size,
                              hipStream_t stream) {
  const float* x     = (const float*)d_in[0];
  const float* w_dq  = (const float*)d_in[1];
  const float* w_uq  = (const float*)d_in[2];
  const float* w_rq  = (const float*)d_in[3];
  const float* w_dkv = (const float*)d_in[4];
  const float* w_rk  = (const float*)d_in[5];
  const float* w_uk  = (const float*)d_in[6];
  const float* w_uv  = (const float*)d_in[7];
  const float* w_o   = (const float*)d_in[8];
  float* out = (float*)d_out;

  __bf16* p = (__bf16*)d_ws;
  __bf16* xb   = p;  p += (size_t)BT * DM;
  __bf16* B1t  = p;  p += (size_t)672 * 1024;
  __bf16* B2t  = p;  p += (size_t)1536 * 384;
  __bf16* B3t  = p;  p += (size_t)2048 * 256;   // w_uk^T | w_uv^T
  __bf16* B4t  = p;  p += (size_t)1024 * 1024;
  __bf16* cqkr = p;  p += (size_t)BT * 672;     // c_q | c_kv | kr
  __bf16* qsqr = p;  p += (size_t)BT * 1536;    // qs | qr
  __bf16* kv   = p;  p += (size_t)BT * 1024;    // ks
  __bf16* vt   = p;  p += (size_t)BT * 1024;    // V^T [b*1024+h*64+d][T]
  __bf16* qb   = p;  p += (size_t)B_ * NH * T_ * DQK;
  __bf16* kb   = p;  p += (size_t)B_ * NH * T_ * DQK;
  __bf16* aob  = xb;   // xb dead after G1

  // Prep: cast x; fused transpose of all 8 weights
  cast_f32_bf16<<<(BT * DM) / 1024, 256, 0, stream>>>(x, xb);
  {
    TDescs td;
    const float* srcs[8] = {w_dq, w_dkv, w_rk, w_uq, w_rq, w_uk, w_uv, w_o};
    __bf16* dsts[8] = {B1t, B1t + (size_t)384 * 1024, B1t + (size_t)640 * 1024,
                       B2t, B2t + (size_t)1024 * 384,
                       B3t, B3t + (size_t)1024 * 256, B4t};
    int Ks[8] = {1024, 1024, 1024, 384, 384, 256, 256, 1024};
    int Ns[8] = {384, 256, 32, 1024, 512, 1024, 1024, 1024};
    int acc = 0;
    for (int i = 0; i < 8; i++) {
      td.src[i] = srcs[i]; td.dst[i] = dsts[i];
      td.K[i] = Ks[i]; td.N[i] = Ns[i];
      td.t0[i] = acc;
      acc += (Ks[i] / 32) * (Ns[i] / 32);
    }
    td.t0[8] = acc;
    transpose_cast_all<<<acc, dim3(32, 8), 0, stream>>>(td);
  }

  // G1: cqkr = xb @ B1t^T   (64x64, BK=64, 4-wave: 704 blocks)  [r14 proven]
  {
    GemmBatch g; g.nd = 1;
    g.d[0] = GemmDesc{xb, B1t, (void*)cqkr, DM, 1024, 672, 1024, 672, 11, 0};
    gemm_multi<__bf16, 64, 64><<<704, 256, 0, stream>>>(g);
  }
  // Fused: G2, G3, VT b0/b1 -> 128x128 tiles (m97 density): 896 blocks
  {
    GemmBatch g; g.nd = 4;
    g.d[0] = GemmDesc{cqkr, B2t, (void*)qsqr, 672, 384, 1536, 384, 1536, 12, 0};
    g.d[1] = GemmDesc{cqkr + 384, B3t, (void*)kv, 672, 256, 1024, 256, 1024, 8, 384};
    g.d[2] = GemmDesc{B3t + (size_t)1024 * 256, cqkr + 384, (void*)vt,
                      256, 672, T_, 256, T_, 16, 640};
    g.d[3] = GemmDesc{B3t + (size_t)1024 * 256, cqkr + (size_t)T_ * 672 + 384,
                      (void*)(vt + (size_t)1024 * T_), 256, 672, T_, 256, T_, 16, 768};
    gemm_multi<__bf16, 128, 128><<<896, 256, 0, stream>>>(g);
  }

  // RoPE + concat + RMS-norm
  assemble_qk<<<(BT * NH) / 4, 256, 0, stream>>>(qsqr, kv, cqkr, qb, kb);

  // Paired-tile fixed-max causal MFMA flash attention (8-wave blocks)
  flash_mfma<<<dim3(T_ / 128, B_ * NH), 512, 0, stream>>>(qb, kb, vt, aob);

  // G4: out = aob @ B4t^T  (fp32 out, 64x64, BK=64, 4-wave: 1024 blocks) [r14]
  {
    GemmBatch g; g.nd = 1;
    g.d[0] = GemmDesc{aob, B4t, (void*)out, DM, 1024, DM, 1024, 1024, 16, 0};
    gemm_multi<float, 64, 64><<<1024, 256, 0, stream>>>(g);
  }
}